// Round 11
// baseline (326.358 us; speedup 1.0000x reference)
//
#include <hip/hip_runtime.h>
#include <hip/hip_bf16.h>

// Mapper: 4 per-word GEMM layers with LN+LeakyReLU between.
// Round 11: the ~60cyc/wave-MFMA + ~1TB/s-fetch invariant across R1-R10 is
// bytes-in-flight starvation: B was always staged with 4B/lane dword loads.
// Now B stages as float4 (16B/lane) along N + in-register k-pair transpose
// (cvt_pk) + ds_write_b32 into the same [n][k] stride-40 LDS layout.
// Geometry: BM=128, BN=64, BK=32, 4 M-stacked waves; A global->reg (16B/lane);
// depth-2 slots; raw lgkm-only barrier; full unroll; counted vmcnt.

typedef unsigned short u16;
typedef __attribute__((ext_vector_type(8))) short bf16x8;
typedef __attribute__((ext_vector_type(4))) float f32x4;

constexpr int CB = 256;      // batch
constexpr int CW = 20;       // words
constexpr int CDIN = 1024;
constexpr int CDOUT = 1024;
constexpr int CH = 1280;
constexpr float CEPS = 1e-5f;
constexpr float CSLOPE = 0.01f;

__device__ __forceinline__ u16 f2bf(float f) {
    union { float f; unsigned u; } v; v.f = f;
    unsigned r = v.u + 0x7fffu + ((v.u >> 16) & 1u);
    return (u16)(r >> 16);
}
// packed pair via HW v_cvt_pk_bf16_f32 (low = a, high = b)
__device__ __forceinline__ unsigned pk2(float a, float b) {
    __hip_bfloat162 h = __float22bfloat162_rn(float2{a, b});
    union { __hip_bfloat162 h; unsigned u; } v; v.h = h;
    return v.u;
}
__device__ __forceinline__ bf16x8 pack8(float4 a, float4 b) {
    union { unsigned u[4]; bf16x8 v; } r;
    r.u[0] = pk2(a.x, a.y); r.u[1] = pk2(a.z, a.w);
    r.u[2] = pk2(b.x, b.y); r.u[3] = pk2(b.z, b.w);
    return r.v;
}

// Workgroup barrier without a vmcnt(0) drain (LDS-visibility only).
__device__ __forceinline__ void bar_keep_vmem() {
    asm volatile("s_waitcnt lgkmcnt(0)" ::: "memory");
    __builtin_amdgcn_s_barrier();
    __builtin_amdgcn_sched_barrier(0);
}

// ---------------------------------------------------------------------------
// GEMM: out[b, w, n] = sum_k A[b, w, k] * Bw[w, k, n] + bias[w, n]
// A: bf16 (u16) or fp32 (AF32), row (b*CW+w), K-contiguous.  Bw: fp32 [W][K][N].
// Tile: BM=128, BN=64, BK=32. 4 waves stacked in M, wave-tile 32x64
// = 2(m) x 4(n) MFMA 16x16x32 = 8 MFMA/wave/step.
// B stage: wave wid owns k-octet [wid*8, wid*8+8). Lane: n-quad (lane&15)*4,
// k-pair wid*8+(lane>>4)*2+{0,1} -> 2 float4 loads (16B/lane). Transpose via
// 4 cvt_pk (k-pair per n) -> 4 ds_write_b32 into [n][k] stride-40-u16 LDS.
// A: 2 parity register slots, global->reg direct (16B/lane).
// Grid: 2 * (N/64) * CW blocks, XCD-swizzled, mb fastest (weight L2 reuse).
// ---------------------------------------------------------------------------
template <int K, int N, bool AF32>
__global__ __launch_bounds__(256, 3) void gemm_kernel(
    const void* __restrict__ Aptr, const float* __restrict__ Bw,
    const float* __restrict__ bias, float* __restrict__ Out)
{
    constexpr int NB  = N / 64;
    constexpr int NK  = K / 32;          // 32 or 40 (even)
    static_assert(NK % 2 == 0 && NK >= 6, "NK must be even");
    constexpr int NWG = 2 * NB * CW;
    constexpr int CPX = NWG / 8;

    __shared__ u16 Bs[2][64 * 40];

    const int t   = threadIdx.x;
    const int bid = blockIdx.x;
    const int logical = (bid & 7) * CPX + (bid >> 3);
    const int mb = logical & 1;
    const int nb = (logical >> 1) % NB;
    const int w  = logical / (2 * NB);

    const int m0g = mb * 128;
    const int n0g = nb * 64;

    const int lane = t & 63;
    const int wid  = t >> 6;
    const int lrow = lane & 15;
    const int kg   = lane >> 4;          // 0..3

    // A-fragment base pointers (16B contiguous k-chunks per lane).
    const int r0 = m0g + wid * 32 + lrow;
    const u16*   a0p  = (const u16*)Aptr   + ((size_t)r0 * CW + w) * K + kg * 8;
    const u16*   a1p  = (const u16*)Aptr   + ((size_t)(r0 + 16) * CW + w) * K + kg * 8;
    const float* a0pf = (const float*)Aptr + ((size_t)r0 * CW + w) * K + kg * 8;
    const float* a1pf = (const float*)Aptr + ((size_t)(r0 + 16) * CW + w) * K + kg * 8;

    // B staging: lane -> n-quad bx4 = (lane&15)*4, k-pair wid*8 + jj*2
    const int bx4 = (lane & 15) * 4;
    const int jj  = lane >> 4;           // 0..3
    const float* bgp = Bw + (size_t)w * K * N
                          + (size_t)(wid * 8 + jj * 2) * N + (n0g + bx4);
    const int woff = bx4 * 40 + wid * 8 + jj * 2;   // u16 index of (bx4, kpair)

    f32x4 acc[2][4];
    #pragma unroll
    for (int i = 0; i < 2; ++i)
        #pragma unroll
        for (int j = 0; j < 4; ++j)
            acc[i][j] = (f32x4){0.f, 0.f, 0.f, 0.f};

    // prefetch slots — static names only
    uint4  ar_A_0, ar_A_1, ar_B_0, ar_B_1;              // bf16 A frags
    float4 af_A_0a, af_A_0b, af_A_1a, af_A_1b;          // fp32 A frags (L1)
    float4 af_B_0a, af_B_0b, af_B_1a, af_B_1b;
    float4 bs_A_0, bs_A_1;                              // B slot A (k even/odd)
    float4 bs_B_0, bs_B_1;                              // B slot B

#define LOADAF(k0, SL)                                                        \
    do {                                                                      \
        if constexpr (AF32) {                                                 \
            af_##SL##_0a = *reinterpret_cast<const float4*>(a0pf + (k0));     \
            af_##SL##_0b = *reinterpret_cast<const float4*>(a0pf + (k0) + 4); \
            af_##SL##_1a = *reinterpret_cast<const float4*>(a1pf + (k0));     \
            af_##SL##_1b = *reinterpret_cast<const float4*>(a1pf + (k0) + 4); \
        } else {                                                              \
            ar_##SL##_0 = *reinterpret_cast<const uint4*>(a0p + (k0));        \
            ar_##SL##_1 = *reinterpret_cast<const uint4*>(a1p + (k0));        \
        }                                                                     \
    } while (0)

// Load B slot: 2 float4 (rows k0+wid*8+jj*2 and +1), 16B per lane.
#define LOADB(k0, SL)                                                         \
    do {                                                                      \
        const float* _pB = bgp + (size_t)(k0) * N;                            \
        bs_##SL##_0 = *reinterpret_cast<const float4*>(_pB);                  \
        bs_##SL##_1 = *reinterpret_cast<const float4*>(_pB + N);              \
    } while (0)

// Transpose+write: for each of the lane's 4 n's, pack its k-pair -> b32.
#define WRITEB(buf, SL)                                                       \
    do {                                                                      \
        unsigned d0 = pk2(bs_##SL##_0.x, bs_##SL##_1.x);                      \
        unsigned d1 = pk2(bs_##SL##_0.y, bs_##SL##_1.y);                      \
        unsigned d2 = pk2(bs_##SL##_0.z, bs_##SL##_1.z);                      \
        unsigned d3 = pk2(bs_##SL##_0.w, bs_##SL##_1.w);                      \
        *reinterpret_cast<unsigned*>(&Bs[buf][woff])          = d0;           \
        *reinterpret_cast<unsigned*>(&Bs[buf][woff + 40])     = d1;           \
        *reinterpret_cast<unsigned*>(&Bs[buf][woff + 80])     = d2;           \
        *reinterpret_cast<unsigned*>(&Bs[buf][woff + 120])    = d3;           \
    } while (0)

#define COMPUTE(buf, SL)                                                      \
    do {                                                                      \
        bf16x8 a0f, a1f;                                                      \
        if constexpr (AF32) {                                                 \
            a0f = pack8(af_##SL##_0a, af_##SL##_0b);                          \
            a1f = pack8(af_##SL##_1a, af_##SL##_1b);                          \
        } else {                                                              \
            a0f = __builtin_bit_cast(bf16x8, ar_##SL##_0);                    \
            a1f = __builtin_bit_cast(bf16x8, ar_##SL##_1);                    \
        }                                                                     \
        bf16x8 bf0 = *reinterpret_cast<const bf16x8*>(                        \
            &Bs[buf][(0 * 16 + lrow) * 40 + kg * 8]);                         \
        bf16x8 bf1 = *reinterpret_cast<const bf16x8*>(                        \
            &Bs[buf][(1 * 16 + lrow) * 40 + kg * 8]);                         \
        bf16x8 bf2 = *reinterpret_cast<const bf16x8*>(                        \
            &Bs[buf][(2 * 16 + lrow) * 40 + kg * 8]);                         \
        bf16x8 bf3 = *reinterpret_cast<const bf16x8*>(                        \
            &Bs[buf][(3 * 16 + lrow) * 40 + kg * 8]);                         \
        acc[0][0] = __builtin_amdgcn_mfma_f32_16x16x32_bf16(a0f, bf0, acc[0][0], 0, 0, 0); \
        acc[1][0] = __builtin_amdgcn_mfma_f32_16x16x32_bf16(a1f, bf0, acc[1][0], 0, 0, 0); \
        acc[0][1] = __builtin_amdgcn_mfma_f32_16x16x32_bf16(a0f, bf1, acc[0][1], 0, 0, 0); \
        acc[1][1] = __builtin_amdgcn_mfma_f32_16x16x32_bf16(a1f, bf1, acc[1][1], 0, 0, 0); \
        acc[0][2] = __builtin_amdgcn_mfma_f32_16x16x32_bf16(a0f, bf2, acc[0][2], 0, 0, 0); \
        acc[1][2] = __builtin_amdgcn_mfma_f32_16x16x32_bf16(a1f, bf2, acc[1][2], 0, 0, 0); \
        acc[0][3] = __builtin_amdgcn_mfma_f32_16x16x32_bf16(a0f, bf3, acc[0][3], 0, 0, 0); \
        acc[1][3] = __builtin_amdgcn_mfma_f32_16x16x32_bf16(a1f, bf3, acc[1][3], 0, 0, 0); \
    } while (0)

    // prologue: buf0 <- step 0; slot A <- step 1, slot B <- step 2;
    // A slots <- steps 0, 1.
    LOADB(0, A);
    WRITEB(0, A);                        // waits only on slot-A loads
    LOADB(1 * 32, A);                    // slot A <- step 1 (consumed phase 0)
    LOADB(2 * 32, B);                    // slot B <- step 2 (consumed phase 1)
    LOADAF(0, A); LOADAF(1 * 32, B);
    bar_keep_vmem();

    // Phase q: WRITEB(slot[q&1] = step q+1 -> buf[(q+1)&1]);
    //          LOADB(step q+3 -> slot[q&1]);  COMPUTE(buf[q&1], aslot[q&1]);
    //          LOADAF(step q+2 -> aslot[q&1]);  barrier.
    // Slot loads live 2 phases -> counted vmcnt(~6), never drained.
    #pragma unroll
    for (int q = 0; q < NK; q += 2) {
        // phase q (even)
        if (q + 1 < NK) WRITEB(1, A);
        if (q + 3 < NK) LOADB((q + 3) * 32, A);
        COMPUTE(0, A);
        if (q + 2 < NK) LOADAF((q + 2) * 32, A);
        bar_keep_vmem();

        // phase q+1 (odd)
        if (q + 2 < NK) WRITEB(0, B);
        if (q + 4 < NK) LOADB((q + 4) * 32, B);
        COMPUTE(1, B);
        if (q + 3 < NK) LOADAF((q + 3) * 32, B);
        bar_keep_vmem();
    }

    // epilogue: + bias, store fp32
    const int rb = (lane >> 4) * 4;
    #pragma unroll
    for (int j = 0; j < 4; ++j) {
        const int gn = n0g + j * 16 + lrow;
        const float bv = bias[(size_t)w * N + gn];
        #pragma unroll
        for (int i = 0; i < 2; ++i) {
            const int gm = m0g + wid * 32 + i * 16 + rb;
            #pragma unroll
            for (int r = 0; r < 4; ++r) {
                Out[((size_t)(gm + r) * CW + w) * N + gn] = acc[i][j][r] + bv;
            }
        }
    }
#undef LOADAF
#undef LOADB
#undef WRITEB
#undef COMPUTE
}

// ---------------------------------------------------------------------------
// LayerNorm + LeakyReLU over last dim (H=1280), writes bf16.
// ---------------------------------------------------------------------------
__global__ __launch_bounds__(320) void ln_lrelu_kernel(
    const float* __restrict__ h, const float* __restrict__ g,
    const float* __restrict__ bta, u16* __restrict__ out)
{
    const int row = blockIdx.x;          // b*CW + w
    const int w = row % CW;
    const int t = threadIdx.x;

    const float4 v = reinterpret_cast<const float4*>(h + (size_t)row * CH)[t];
    float s  = v.x + v.y + v.z + v.w;
    float sq = v.x * v.x + v.y * v.y + v.z * v.z + v.w * v.w;
    #pragma unroll
    for (int o = 32; o > 0; o >>= 1) {
        s  += __shfl_down(s, o, 64);
        sq += __shfl_down(sq, o, 64);
    }
    __shared__ float ss[5], sg[5];
    const int lane = t & 63, wv = t >> 6;
    if (lane == 0) { ss[wv] = s; sg[wv] = sq; }
    __syncthreads();
    float S = 0.f, Q = 0.f;
    #pragma unroll
    for (int i = 0; i < 5; ++i) { S += ss[i]; Q += sg[i]; }
    const float mean = S * (1.0f / CH);
    const float var  = Q * (1.0f / CH) - mean * mean;
    const float rstd = rsqrtf(var + CEPS);

    const float4 gg = reinterpret_cast<const float4*>(g   + (size_t)w * CH)[t];
    const float4 bb = reinterpret_cast<const float4*>(bta + (size_t)w * CH)[t];
    float4 y;
    y.x = (v.x - mean) * rstd * gg.x + bb.x;
    y.y = (v.y - mean) * rstd * gg.y + bb.y;
    y.z = (v.z - mean) * rstd * gg.z + bb.z;
    y.w = (v.w - mean) * rstd * gg.w + bb.w;
    y.x = y.x >= 0.f ? y.x : CSLOPE * y.x;
    y.y = y.y >= 0.f ? y.y : CSLOPE * y.y;
    y.z = y.z >= 0.f ? y.z : CSLOPE * y.z;
    y.w = y.w >= 0.f ? y.w : CSLOPE * y.w;
    ushort4 o4;
    o4.x = f2bf(y.x); o4.y = f2bf(y.y); o4.z = f2bf(y.z); o4.w = f2bf(y.w);
    reinterpret_cast<ushort4*>(out + (size_t)row * CH)[t] = o4;
}

extern "C" void kernel_launch(void* const* d_in, const int* in_sizes, int n_in,
                              void* d_out, int out_size, void* d_ws, size_t ws_size,
                              hipStream_t stream)
{
    const float* embs = (const float*)d_in[0];
    const float* W1  = (const float*)d_in[1];
    const float* b1  = (const float*)d_in[2];
    const float* g1  = (const float*)d_in[3];
    const float* bn1 = (const float*)d_in[4];
    const float* W2  = (const float*)d_in[5];
    const float* b2  = (const float*)d_in[6];
    const float* g2  = (const float*)d_in[7];
    const float* bn2 = (const float*)d_in[8];
    const float* W3  = (const float*)d_in[9];
    const float* b3  = (const float*)d_in[10];
    const float* g3  = (const float*)d_in[11];
    const float* bn3 = (const float*)d_in[12];
    const float* W4  = (const float*)d_in[13];
    const float* b4  = (const float*)d_in[14];

    char* ws = (char*)d_ws;
    float* h_raw = (float*)ws;                               // B*W*H*4  = 26,214,400
    u16*   a_bf  = (u16*)(ws + 26214400);                    // B*W*H*2  = 13,107,200

    // Layer 1: [256x1024] @ [1024x1280], A = embs fp32 (cvt at consume)
    gemm_kernel<CDIN, CH, true><<<2 * (CH / 64) * CW, 256, 0, stream>>>(embs, W1, b1, h_raw);
    ln_lrelu_kernel<<<CB * CW, 320, 0, stream>>>(h_raw, g1, bn1, a_bf);
    // Layer 2: [256x1280] @ [1280x1280]
    gemm_kernel<CH, CH, false><<<2 * (CH / 64) * CW, 256, 0, stream>>>(a_bf, W2, b2, h_raw);
    ln_lrelu_kernel<<<CB * CW, 320, 0, stream>>>(h_raw, g2, bn2, a_bf);
    // Layer 3: [256x1280] @ [1280x1280]
    gemm_kernel<CH, CH, false><<<2 * (CH / 64) * CW, 256, 0, stream>>>(a_bf, W3, b3, h_raw);
    ln_lrelu_kernel<<<CB * CW, 320, 0, stream>>>(h_raw, g3, bn3, a_bf);
    // Layer 4: [256x1280] @ [1280x1024] -> d_out (fp32)
    gemm_kernel<CH, CDOUT, false><<<2 * (CDOUT / 64) * CW, 256, 0, stream>>>(a_bf, W4, b4, (float*)d_out);
}